// Round 5
// baseline (1588.255 us; speedup 1.0000x reference)
//
#include <hip/hip_runtime.h>
#include <math.h>

#define HP 264
#define WP 264
#define NPIX (HP*WP)          // 69696
#define CH 64
#define BATCH 4
#define BCN (BATCH*CH)        // 256
#define NROWS (BCN*HP)        // 67584
#define H0 256
#define W0 256

// ---------------- tables ----------------
__global__ void init_tables(float* __restrict__ BX, float* __restrict__ BI,
                            float2* __restrict__ csY, float2* __restrict__ csYT) {
  int idx = blockIdx.x*256 + threadIdx.x;
  if (idx >= 264*64) return;
  const float w = 6.28318530717958647692f / 264.0f;
  {
    int x = idx >> 6, k = idx & 63;
    int m = k >> 1;
    float s, c; sincosf(w * (float)((x*m) % 264), &s, &c);
    BX[idx] = (k & 1) ? -s : c;
    float sc = (m ? 2.0f : 1.0f) / 69696.0f;
    float v = (k & 1) ? -sc*s : sc*c;
    if (k == 1) v = 0.f;
    BI[(size_t)k*264 + x] = v;
  }
  {
    int y = idx >> 6, j = idx & 63;
    int ky = (j < 32) ? j : (200 + j);
    float s, c; sincosf(w * (float)((y*ky) % 264), &s, &c);
    csY[y*64 + j] = make_float2(c, s);
    csYT[j*264 + y] = make_float2(c, s);
  }
}

// Pre-transpose weights so per-ci weight rows are CONTIGUOUS:
// WcT[k][ci][co]  <- conv_w[k][co][ci]
// W1T[k][ci][j]   <- mlp_w1[k][j][ci]
// W2T[k][j][co]   <- mlp_w2[k][co][j]
__global__ void transpose_weights(const float* __restrict__ Wc,
                                  const float* __restrict__ W1,
                                  const float* __restrict__ W2,
                                  float* __restrict__ WcT,
                                  float* __restrict__ W1T,
                                  float* __restrict__ W2T) {
  int idx = blockIdx.x*256 + threadIdx.x;
  if (idx < 3*4096) {
    int k = idx/4096, r = idx%4096, ci = r>>6, co = r&63;
    WcT[idx] = Wc[k*4096 + co*64 + ci];
  }
  if (idx < 3*8192) {
    int k = idx/8192, r = idx%8192, ci = r>>7, j = r&127;
    W1T[idx] = W1[k*8192 + j*64 + ci];
  }
  if (idx < 3*8192) {
    int k = idx/8192, r = idx%8192, j = r>>6, co = r&63;
    W2T[idx] = W2[k*8192 + co*128 + j];
  }
}

__device__ __forceinline__ float gelu_erf(float v) {
  return 0.5f * v * (1.0f + erff(v * 0.70710678118654752440f));
}

// ---------------- lift ----------------
__global__ __launch_bounds__(256) void lift_kernel(
    const float* __restrict__ xin,
    const float* __restrict__ w1, const float* __restrict__ b1,
    const float* __restrict__ w2, const float* __restrict__ b2,
    float* __restrict__ xbuf) {
  int b = blockIdx.y;
  int flat = blockIdx.x*256 + threadIdx.x;
  if (flat >= NPIX) return;
  int y = flat / WP, x = flat - y*WP;
  float* outp = xbuf + (size_t)b*CH*NPIX + flat;
  if (y >= H0 || x >= W0) {
    for (int c = 0; c < CH; ++c) outp[c*NPIX] = 0.f;
    return;
  }
  float in[5];
  const float* xb = xin + ((size_t)b*3)*H0*W0 + y*W0 + x;
  in[0] = xb[0];
  in[1] = xb[H0*W0];
  in[2] = xb[2*H0*W0];
  in[3] = (float)y * (1.0f/255.0f);
  in[4] = (float)x * (1.0f/255.0f);
  float t[32];
  #pragma unroll
  for (int h = 0; h < 32; ++h) {
    float s = b1[h];
    #pragma unroll
    for (int i = 0; i < 5; ++i) s += w1[h*5+i]*in[i];
    t[h] = gelu_erf(s);
  }
  for (int c = 0; c < CH; ++c) {
    float s = b2[c];
    #pragma unroll
    for (int h = 0; h < 32; ++h) s += w2[c*32+h]*t[h];
    outp[c*NPIX] = s;
  }
}

// ---------------- fused conv1x1(64->64) -> mlp1(64->128)+gelu -> mlp2(128->64)
// Round-2 geometry (64-px tile, 4 waves x 16/32 out-channels) but weights
// streamed through LDS (wave-uniform ds_read_b128 broadcasts) instead of
// SMEM s_loads: all inner-loop memory is in-order DS, so the compiler uses
// fine-grained lgkmcnt(N) waits -- no out-of-order-SMEM lgkmcnt(0) drains.
// Weights staged in 2048-float quarters, ping-ponged between wq[0]/wq[1];
// each compute phase prefetches the next quarter into the idle buffer.
// LDS = 16+16+16 = 48 KB -> 3 blocks/CU.

#define LOADW(DST, SRC) do { \
    const float4* s_ = (const float4*)(SRC); \
    float4* d_ = (float4*)(DST); \
    d_[tid] = s_[tid]; d_[256+tid] = s_[256+tid]; \
  } while (0)

#define S1HALF(WBUF, CIOFS) \
  _Pragma("unroll 4") \
  for (int ci = 0; ci < 32; ++ci) { \
    float xv = sA[(ci+(CIOFS))*64 + p]; \
    const float4* w4 = (const float4*)((WBUF) + ci*64 + cg16); \
    float4 wa=w4[0], wb2=w4[1], wc2=w4[2], wd2=w4[3]; \
    acc0[0]=fmaf(xv,wa.x,acc0[0]);   acc0[1]=fmaf(xv,wa.y,acc0[1]); \
    acc0[2]=fmaf(xv,wa.z,acc0[2]);   acc0[3]=fmaf(xv,wa.w,acc0[3]); \
    acc0[4]=fmaf(xv,wb2.x,acc0[4]);  acc0[5]=fmaf(xv,wb2.y,acc0[5]); \
    acc0[6]=fmaf(xv,wb2.z,acc0[6]);  acc0[7]=fmaf(xv,wb2.w,acc0[7]); \
    acc0[8]=fmaf(xv,wc2.x,acc0[8]);  acc0[9]=fmaf(xv,wc2.y,acc0[9]); \
    acc0[10]=fmaf(xv,wc2.z,acc0[10]); acc0[11]=fmaf(xv,wc2.w,acc0[11]); \
    acc0[12]=fmaf(xv,wd2.x,acc0[12]); acc0[13]=fmaf(xv,wd2.y,acc0[13]); \
    acc0[14]=fmaf(xv,wd2.z,acc0[14]); acc0[15]=fmaf(xv,wd2.w,acc0[15]); \
  }

#define S2QUART(WBUF, CIOFS) \
  _Pragma("unroll 2") \
  for (int ci = 0; ci < 16; ++ci) { \
    float xv = sB[(ci+(CIOFS))*64 + p]; \
    const float4* w4 = (const float4*)((WBUF) + ci*128 + cg32); \
    _Pragma("unroll") \
    for (int q = 0; q < 8; ++q) { \
      float4 wv = w4[q]; \
      a1[4*q]   = fmaf(xv, wv.x, a1[4*q]); \
      a1[4*q+1] = fmaf(xv, wv.y, a1[4*q+1]); \
      a1[4*q+2] = fmaf(xv, wv.z, a1[4*q+2]); \
      a1[4*q+3] = fmaf(xv, wv.w, a1[4*q+3]); \
    } \
  }

#define S3QUART(WBUF, SRC, ROWOFS) \
  _Pragma("unroll 4") \
  for (int j = 0; j < 32; ++j) { \
    float xv = (SRC)[(j+(ROWOFS))*64 + p]; \
    const float4* w4 = (const float4*)((WBUF) + j*64 + cg16); \
    float4 wa=w4[0], wb2=w4[1], wc2=w4[2], wd2=w4[3]; \
    acc2[0]=fmaf(xv,wa.x,acc2[0]);   acc2[1]=fmaf(xv,wa.y,acc2[1]); \
    acc2[2]=fmaf(xv,wa.z,acc2[2]);   acc2[3]=fmaf(xv,wa.w,acc2[3]); \
    acc2[4]=fmaf(xv,wb2.x,acc2[4]);  acc2[5]=fmaf(xv,wb2.y,acc2[5]); \
    acc2[6]=fmaf(xv,wb2.z,acc2[6]);  acc2[7]=fmaf(xv,wb2.w,acc2[7]); \
    acc2[8]=fmaf(xv,wc2.x,acc2[8]);  acc2[9]=fmaf(xv,wc2.y,acc2[9]); \
    acc2[10]=fmaf(xv,wc2.z,acc2[10]); acc2[11]=fmaf(xv,wc2.w,acc2[11]); \
    acc2[12]=fmaf(xv,wd2.x,acc2[12]); acc2[13]=fmaf(xv,wd2.y,acc2[13]); \
    acc2[14]=fmaf(xv,wd2.z,acc2[14]); acc2[15]=fmaf(xv,wd2.w,acc2[15]); \
  }

__global__ __launch_bounds__(256, 3) void convmlp_kernel(
    const float* __restrict__ X, float* __restrict__ Hb,
    const float* __restrict__ WcT, const float* __restrict__ cb,
    const float* __restrict__ W1T, const float* __restrict__ b1,
    const float* __restrict__ W2T, const float* __restrict__ b2) {
  __shared__ float sA[4096];     // input tile (ci-major), later gelu j<64
  __shared__ float sB[4096];     // conv output tile, later gelu j>=64
  __shared__ float wq[2][2048];  // ping-pong weight quarters (8 KB each)
  int blk = blockIdx.x;
  int b = blk / 1089;
  int flat0 = (blk - b*1089) * 64;
  int tid = threadIdx.x;
  int p = tid & 63;
  int cg = __builtin_amdgcn_readfirstlane(tid >> 6);  // 0..3 wave-uniform
  int cg16 = cg*16, cg32 = cg*32;

  // PRE: stage input tile + stage1 weight half 0
  LOADW(wq[0], WcT);
  const float* xb = X + (size_t)b*CH*NPIX + flat0;
  #pragma unroll
  for (int i = 0; i < 16; ++i) {
    int idx = i*256 + tid;
    int ci = idx >> 6, pp = idx & 63;
    sA[idx] = xb[ci*NPIX + pp];
  }
  float acc0[16];
  #pragma unroll
  for (int i = 0; i < 16; ++i) acc0[i] = cb[cg16+i];
  __syncthreads();

  // A: stage1 ci 0..31 (wq0); prefetch stage1 half 1 -> wq1
  LOADW(wq[1], WcT + 2048);
  S1HALF(wq[0], 0)
  __syncthreads();

  // B: stage1 ci 32..63 (wq1); prefetch stage2 q0 -> wq0; write x2 -> sB
  LOADW(wq[0], W1T);
  S1HALF(wq[1], 32)
  #pragma unroll
  for (int i = 0; i < 16; ++i) sB[(cg16+i)*64+p] = acc0[i];
  __syncthreads();

  // C..F: stage2 in quarters of 16 ci
  float a1[32];
  #pragma unroll
  for (int j = 0; j < 32; ++j) a1[j] = b1[cg32+j];
  LOADW(wq[1], W1T + 2048);     // C: compute q0 (wq0), prefetch q1
  S2QUART(wq[0], 0)
  __syncthreads();
  LOADW(wq[0], W1T + 4096);     // D: compute q1 (wq1), prefetch q2
  S2QUART(wq[1], 16)
  __syncthreads();
  LOADW(wq[1], W1T + 6144);     // E: compute q2 (wq0), prefetch q3
  S2QUART(wq[0], 32)
  __syncthreads();
  LOADW(wq[0], W2T);            // F: compute q3 (wq1), prefetch stage3 q0
  S2QUART(wq[1], 48)
  __syncthreads();

  // G: gelu -> sA (ch<64) / sB (ch>=64); prefetch stage3 q1 -> wq1
  LOADW(wq[1], W2T + 2048);
  if (cg < 2) {
    #pragma unroll
    for (int j = 0; j < 32; ++j) sA[(cg32+j)*64+p] = gelu_erf(a1[j]);
  } else {
    #pragma unroll
    for (int j = 0; j < 32; ++j) sB[((cg-2)*32+j)*64+p] = gelu_erf(a1[j]);
  }
  __syncthreads();

  // H..K: stage3 in quarters of 32 j
  float acc2[16];
  #pragma unroll
  for (int i = 0; i < 16; ++i) acc2[i] = b2[cg16+i];
  S3QUART(wq[0], sA, 0)         // H: j 0..31 (no prefetch slot free)
  __syncthreads();
  LOADW(wq[0], W2T + 4096);     // I: j 32..63 (wq1), prefetch q2
  S3QUART(wq[1], sA, 32)
  __syncthreads();
  LOADW(wq[1], W2T + 6144);     // J: j 64..95 (wq0), prefetch q3
  S3QUART(wq[0], sB, 0)
  __syncthreads();
  S3QUART(wq[1], sB, 32)        // K: j 96..127
  float* hb = Hb + (size_t)b*CH*NPIX + flat0;
  #pragma unroll
  for (int i = 0; i < 16; ++i) hb[(cg16+i)*NPIX + p] = acc2[i];
}

// ---------------- fwd-x DFT: F1[r][k] = sum_x X[r][x]*BX[x][k]
// k split 4-way across the block's 4 waves, w forced wave-uniform via
// readfirstlane so all BX loads scalarize to s_load_dwordx16 (SGPR operands,
// no VGPR/VMEM pressure).
__global__ __launch_bounds__(256, 4) void fwd_x_kernel(const float* __restrict__ X,
    float* __restrict__ F1, const float* __restrict__ BX) {
  int tid = threadIdx.x;
  int lane = tid & 63;
  int w = __builtin_amdgcn_readfirstlane(tid >> 6);   // k-chunk 0..3
  int k0 = w * 16;
  int r = blockIdx.x*64 + lane;
  const float* xr = X + (size_t)r*264;
  float acc[16];
  #pragma unroll
  for (int k = 0; k < 16; ++k) acc[k] = 0.f;
  float4 u = ((const float4*)xr)[0];
  float4 v = ((const float4*)xr)[1];
  #pragma unroll 1
  for (int xc = 0; xc < 33; ++xc) {
    int nc = (xc < 32) ? xc + 1 : 32;
    float4 nu = ((const float4*)xr)[nc*2];
    float4 nv = ((const float4*)xr)[nc*2+1];
    float xvv[8] = {u.x,u.y,u.z,u.w,v.x,v.y,v.z,v.w};
    #pragma unroll
    for (int i = 0; i < 8; ++i) {
      const float* B = BX + (xc*8+i)*64 + k0;
      #pragma unroll
      for (int k = 0; k < 16; ++k) acc[k] = fmaf(xvv[i], B[k], acc[k]);
    }
    u = nu; v = nv;
  }
  float* fr = F1 + (size_t)r*64 + k0;
  #pragma unroll
  for (int q = 0; q < 4; ++q)
    ((float4*)fr)[q] = make_float4(acc[4*q],acc[4*q+1],acc[4*q+2],acc[4*q+3]);
}

// ---------------- fwd-y DFT
// kx split 4-way across blockIdx.y; w (y-chunk) readfirstlane'd so the
// F1 row loads (wave-uniform addresses) scalarize to s_load_dwordx16.
__global__ __launch_bounds__(256, 4) void fwd_y_kernel(const float* __restrict__ F1,
    float* __restrict__ F2, const float2* __restrict__ csY) {
  __shared__ float sT[4][16][64];   // [y-chunk wave][k local][j]
  int tid = threadIdx.x, lane = tid & 63;
  int w = __builtin_amdgcn_readfirstlane(tid >> 6);
  int bc = blockIdx.x;
  int h = blockIdx.y;               // kx chunk 0..3
  float acc[16];
  #pragma unroll
  for (int k = 0; k < 16; ++k) acc[k] = 0.f;
  const float* f1b = F1 + (size_t)bc*264*64 + h*16;
  for (int y = w*66; y < (w+1)*66; ++y) {
    float2 cs = csY[y*64 + lane];
    float c = cs.x, s = cs.y, ns = -s;
    const float* fr = f1b + y*64;
    #pragma unroll
    for (int t = 0; t < 8; ++t) {
      float fre = fr[2*t], fim = fr[2*t+1];
      acc[2*t]   = fmaf(c, fre, fmaf(s,  fim, acc[2*t]));
      acc[2*t+1] = fmaf(c, fim, fmaf(ns, fre, acc[2*t+1]));
    }
  }
  #pragma unroll
  for (int k = 0; k < 16; ++k) sT[w][k][lane] = acc[k];
  __syncthreads();
  int j = tid >> 2, kg = tid & 3;
  float* out = F2 + (size_t)bc*4096 + j*64 + h*16 + kg*4;
  float o[4];
  #pragma unroll
  for (int t = 0; t < 4; ++t)
    o[t] = sT[0][kg*4+t][j] + sT[1][kg*4+t][j] + sT[2][kg*4+t][j] + sT[3][kg*4+t][j];
  *((float4*)out) = make_float4(o[0],o[1],o[2],o[3]);
}

// ---------------- per-mode channel mixing; weights read once, all 4 batch
// elements accumulated per thread.
__global__ __launch_bounds__(256) void mix_kernel(const float2* __restrict__ F2,
    float2* __restrict__ S,
    const float* __restrict__ w1r, const float* __restrict__ w1i,
    const float* __restrict__ w2r, const float* __restrict__ w2i) {
  int tid = threadIdx.x;
  int m = tid & 63;
  int cl = tid >> 6;
  int mode = blockIdx.x*64 + m;
  int co = blockIdx.y*4 + cl;
  int moff = mode & 1023;
  const float* wr = ((mode < 1024) ? w1r : w2r) + co*1024 + moff;
  const float* wi = ((mode < 1024) ? w1i : w2i) + co*1024 + moff;
  const float2* f2 = F2 + mode;
  float sr[4], si[4];
  #pragma unroll
  for (int b = 0; b < 4; ++b) { sr[b] = 0.f; si[b] = 0.f; }
  for (int ci = 0; ci < 64; ++ci) {
    float wrv = wr[(size_t)ci*65536];
    float wiv = wi[(size_t)ci*65536];
    #pragma unroll
    for (int b = 0; b < 4; ++b) {
      float2 f = f2[(size_t)(b*CH + ci)*2048];
      sr[b] = fmaf(f.x, wrv, fmaf(-f.y, wiv, sr[b]));
      si[b] = fmaf(f.x, wiv, fmaf( f.y, wrv, si[b]));
    }
  }
  #pragma unroll
  for (int b = 0; b < 4; ++b)
    S[((size_t)b*CH + co)*2048 + mode] = make_float2(sr[b], si[b]);
}

// ---------------- inv-y DFT
// kx split 4-way across the block's 4 waves; w readfirstlane'd so the S row
// loads (wave-uniform) scalarize to s_load_dwordx16.
__global__ __launch_bounds__(256, 4) void inv_y_kernel(const float* __restrict__ S,
    float* __restrict__ Z, const float2* __restrict__ csYT) {
  int tid = threadIdx.x;
  int lane = tid & 63;
  int w = __builtin_amdgcn_readfirstlane(tid >> 6);   // kx chunk 0..3
  int bc = blockIdx.y;
  int y = blockIdx.x*64 + lane;
  int yy = (y < 264) ? y : 263;
  float acc[16];
  #pragma unroll
  for (int k = 0; k < 16; ++k) acc[k] = 0.f;
  const float* sb = S + (size_t)bc*4096 + w*16;
  for (int j = 0; j < 64; ++j) {
    float2 cs = csYT[j*264 + yy];
    float c = cs.x, s = cs.y, ns = -s;
    const float* sr = sb + j*64;
    #pragma unroll
    for (int t = 0; t < 8; ++t) {
      float sre = sr[2*t], sim = sr[2*t+1];
      acc[2*t]   = fmaf(c, sre, fmaf(ns, sim, acc[2*t]));
      acc[2*t+1] = fmaf(s, sre, fmaf(c,  sim, acc[2*t+1]));
    }
  }
  if (y < 264) {
    float* zr = Z + ((size_t)bc*264 + y)*64 + w*16;
    #pragma unroll
    for (int q = 0; q < 4; ++q)
      ((float4*)zr)[q] = make_float4(acc[4*q],acc[4*q+1],acc[4*q+2],acc[4*q+3]);
  }
}

// ---------------- inv-x irfft + Hb add + store (crop on last layer)
__global__ __launch_bounds__(128) void inv_x_kernel(const float* __restrict__ Z,
    const float* __restrict__ Hb, float* __restrict__ Xout, float* __restrict__ Dout,
    const float* __restrict__ BI, int last) {
  int r = blockIdx.x*128 + threadIdx.x;
  int xh = blockIdx.y;
  float a[64];
  const float4* zp = (const float4*)(Z + (size_t)r*64);
  #pragma unroll
  for (int q = 0; q < 16; ++q) {
    float4 t = zp[q];
    a[4*q] = t.x; a[4*q+1] = t.y; a[4*q+2] = t.z; a[4*q+3] = t.w;
  }
  int y = r % 264;
  int bc = r / 264;
  const float* hbr = Hb + (size_t)r*264;
  float* xo = Xout + (size_t)r*264;
  float* dor = Dout + ((size_t)bc*256 + y)*256;
  #pragma unroll 1
  for (int cch = 0; cch < 4; ++cch) {
    int x0 = xh*128 + cch*32;
    float acc[32];
    #pragma unroll
    for (int s = 0; s < 32; ++s) acc[s] = 0.f;
    #pragma unroll
    for (int k = 0; k < 64; ++k) {
      const float* B = BI + (size_t)k*264 + x0;
      #pragma unroll
      for (int s = 0; s < 32; ++s) acc[s] = fmaf(a[k], B[s], acc[s]);
    }
    if (!last) {
      #pragma unroll
      for (int q = 0; q < 8; ++q) {
        float4 h = ((const float4*)(hbr + x0))[q];
        ((float4*)(xo + x0))[q] =
          make_float4(h.x+acc[4*q], h.y+acc[4*q+1], h.z+acc[4*q+2], h.w+acc[4*q+3]);
      }
    } else if (y < 256) {
      #pragma unroll
      for (int q = 0; q < 8; ++q) {
        float4 h = ((const float4*)(hbr + x0))[q];
        ((float4*)(dor + x0))[q] =
          make_float4(h.x+acc[4*q], h.y+acc[4*q+1], h.z+acc[4*q+2], h.w+acc[4*q+3]);
      }
    }
  }
  if (xh == 1 && !last) {
    float acc[8];
    #pragma unroll
    for (int s = 0; s < 8; ++s) acc[s] = 0.f;
    #pragma unroll
    for (int k = 0; k < 64; ++k) {
      const float* B = BI + (size_t)k*264 + 256;
      #pragma unroll
      for (int s = 0; s < 8; ++s) acc[s] = fmaf(a[k], B[s], acc[s]);
    }
    #pragma unroll
    for (int q = 0; q < 2; ++q) {
      float4 h = ((const float4*)(hbr + 256))[q];
      ((float4*)(xo + 256))[q] =
        make_float4(h.x+acc[4*q], h.y+acc[4*q+1], h.z+acc[4*q+2], h.w+acc[4*q+3]);
    }
  }
}

extern "C" void kernel_launch(void* const* d_in, const int* in_sizes, int n_in,
                              void* d_out, int out_size, void* d_ws, size_t ws_size,
                              hipStream_t stream) {
  (void)in_sizes; (void)n_in; (void)out_size; (void)ws_size;
  const float* x_in   = (const float*)d_in[0];
  const float* lw1    = (const float*)d_in[1];
  const float* lb1    = (const float*)d_in[2];
  const float* lw2    = (const float*)d_in[3];
  const float* lb2    = (const float*)d_in[4];
  const float* conv_w = (const float*)d_in[5];
  const float* conv_b = (const float*)d_in[6];
  const float* mlp_w1 = (const float*)d_in[7];
  const float* mlp_b1 = (const float*)d_in[8];
  const float* mlp_w2 = (const float*)d_in[9];
  const float* mlp_b2 = (const float*)d_in[10];
  const float* sw1r   = (const float*)d_in[11];
  const float* sw1i   = (const float*)d_in[12];
  const float* sw2r   = (const float*)d_in[13];
  const float* sw2i   = (const float*)d_in[14];
  float* dout = (float*)d_out;

  float* ws = (float*)d_ws;
  size_t off = 0;
  float*  xbuf = ws + off;          off += (size_t)BCN*NPIX;
  float*  hbuf = ws + off;          off += (size_t)BCN*NPIX;
  float*  F1   = ws + off;          off += (size_t)NROWS*64;   // also Z
  float*  F2   = ws + off;          off += (size_t)BCN*4096;
  float*  S    = ws + off;          off += (size_t)BCN*4096;
  float*  BX   = ws + off;          off += 264*64;
  float*  BI   = ws + off;          off += 264*64;
  float2* csY  = (float2*)(ws+off); off += 264*64*2;
  float2* csYT = (float2*)(ws+off); off += 264*64*2;
  float*  WcT  = ws + off;          off += 3*4096;
  float*  W1T  = ws + off;          off += 3*8192;
  float*  W2T  = ws + off;          off += 3*8192;

  init_tables<<<66, 256, 0, stream>>>(BX, BI, csY, csYT);
  transpose_weights<<<96, 256, 0, stream>>>(conv_w, mlp_w1, mlp_w2, WcT, W1T, W2T);
  lift_kernel<<<dim3(273, 4), 256, 0, stream>>>(x_in, lw1, lb1, lw2, lb2, xbuf);

  for (int k = 0; k < 3; ++k) {
    convmlp_kernel<<<4356, 256, 0, stream>>>(xbuf, hbuf,
        WcT + k*4096, conv_b + k*64,
        W1T + k*8192, mlp_b1 + k*128,
        W2T + k*8192, mlp_b2 + k*64);
    fwd_x_kernel<<<1056, 256, 0, stream>>>(xbuf, F1, BX);
    fwd_y_kernel<<<dim3(256, 4), 256, 0, stream>>>(F1, F2, csY);
    mix_kernel<<<dim3(32, 16), 256, 0, stream>>>((const float2*)F2, (float2*)S,
        sw1r + (size_t)k*4194304, sw1i + (size_t)k*4194304,
        sw2r + (size_t)k*4194304, sw2i + (size_t)k*4194304);
    inv_y_kernel<<<dim3(5, 256), 256, 0, stream>>>(S, F1, csYT);
    inv_x_kernel<<<dim3(528, 2), 128, 0, stream>>>(F1, hbuf, xbuf, dout, BI, (k==2)?1:0);
  }
}

// Round 6
// 1312.605 us; speedup vs baseline: 1.2100x; 1.2100x over previous
//
#include <hip/hip_runtime.h>
#include <math.h>

#define HP 264
#define WP 264
#define NPIX (HP*WP)          // 69696
#define CH 64
#define BATCH 4
#define BCN (BATCH*CH)        // 256
#define NROWS (BCN*HP)        // 67584
#define H0 256
#define W0 256

// ---------------- tables ----------------
__global__ void init_tables(float* __restrict__ BX, float* __restrict__ BI,
                            float2* __restrict__ csY, float2* __restrict__ csYT) {
  int idx = blockIdx.x*256 + threadIdx.x;
  if (idx >= 264*64) return;
  const float w = 6.28318530717958647692f / 264.0f;
  {
    int x = idx >> 6, k = idx & 63;
    int m = k >> 1;
    float s, c; sincosf(w * (float)((x*m) % 264), &s, &c);
    BX[idx] = (k & 1) ? -s : c;
    float sc = (m ? 2.0f : 1.0f) / 69696.0f;
    float v = (k & 1) ? -sc*s : sc*c;
    if (k == 1) v = 0.f;
    BI[(size_t)k*264 + x] = v;
  }
  {
    int y = idx >> 6, j = idx & 63;
    int ky = (j < 32) ? j : (200 + j);
    float s, c; sincosf(w * (float)((y*ky) % 264), &s, &c);
    csY[y*64 + j] = make_float2(c, s);
    csYT[j*264 + y] = make_float2(c, s);
  }
}

// conv(64->64) and mlp1(64->128) are both linear with nothing between them,
// and the conv output feeds nothing else -> fold them once at setup:
//   WfT[k][ci][j] = sum_co mlp_w1[k][j][co] * conv_w[k][co][ci]
//   bf[k][j]      = sum_co mlp_w1[k][j][co] * conv_b[k][co] + mlp_b1[k][j]
// Removes 20% of convmlp's MACs and one LDS round-trip + 2 barriers.
__global__ void fuse_weights(const float* __restrict__ Wc,
                             const float* __restrict__ cbias,
                             const float* __restrict__ W1,
                             const float* __restrict__ b1,
                             float* __restrict__ WfT,
                             float* __restrict__ bfo) {
  int idx = blockIdx.x*256 + threadIdx.x;
  if (idx < 3*8192) {
    int k = idx / 8192, r = idx % 8192, ci = r >> 7, j = r & 127;
    const float* w1r = W1 + k*8192 + j*64;
    const float* wcc = Wc + k*4096 + ci;
    float s = 0.f;
    for (int co = 0; co < 64; ++co) s += w1r[co] * wcc[co*64];
    WfT[idx] = s;
  }
  if (idx < 3*128) {
    int k = idx >> 7, j = idx & 127;
    const float* w1r = W1 + k*8192 + j*64;
    const float* cbk = cbias + k*64;
    float s = b1[idx];
    for (int co = 0; co < 64; ++co) s += w1r[co] * cbk[co];
    bfo[idx] = s;
  }
}

// W2T[k][j][co] <- mlp_w2[k][co][j]  (contiguous per-j weight rows)
__global__ void transpose_w2(const float* __restrict__ W2,
                             float* __restrict__ W2T) {
  int idx = blockIdx.x*256 + threadIdx.x;
  if (idx < 3*8192) {
    int k = idx/8192, r = idx%8192, j = r>>6, co = r&63;
    W2T[idx] = W2[k*8192 + co*128 + j];
  }
}

__device__ __forceinline__ float gelu_erf(float v) {
  return 0.5f * v * (1.0f + erff(v * 0.70710678118654752440f));
}

// ---------------- lift ----------------
__global__ __launch_bounds__(256) void lift_kernel(
    const float* __restrict__ xin,
    const float* __restrict__ w1, const float* __restrict__ b1,
    const float* __restrict__ w2, const float* __restrict__ b2,
    float* __restrict__ xbuf) {
  int b = blockIdx.y;
  int flat = blockIdx.x*256 + threadIdx.x;
  if (flat >= NPIX) return;
  int y = flat / WP, x = flat - y*WP;
  float* outp = xbuf + (size_t)b*CH*NPIX + flat;
  if (y >= H0 || x >= W0) {
    for (int c = 0; c < CH; ++c) outp[c*NPIX] = 0.f;
    return;
  }
  float in[5];
  const float* xb = xin + ((size_t)b*3)*H0*W0 + y*W0 + x;
  in[0] = xb[0];
  in[1] = xb[H0*W0];
  in[2] = xb[2*H0*W0];
  in[3] = (float)y * (1.0f/255.0f);
  in[4] = (float)x * (1.0f/255.0f);
  float t[32];
  #pragma unroll
  for (int h = 0; h < 32; ++h) {
    float s = b1[h];
    #pragma unroll
    for (int i = 0; i < 5; ++i) s += w1[h*5+i]*in[i];
    t[h] = gelu_erf(s);
  }
  for (int c = 0; c < CH; ++c) {
    float s = b2[c];
    #pragma unroll
    for (int h = 0; h < 32; ++h) s += w2[c*32+h]*t[h];
    outp[c*NPIX] = s;
  }
}

// ---------------- fused (conv+mlp1)(64->128) + gelu -> mlp2(128->64)
// Round-2 structure (the best of 4 tried: s_load weights 183us vs VMEM 684 /
// 128px 241 / LDS-stream 246), minus the folded-away stage1.
__global__ __launch_bounds__(256) void convmlp_kernel(
    const float* __restrict__ X, float* __restrict__ Hb,
    const float* __restrict__ WfT, const float* __restrict__ bf,
    const float* __restrict__ W2T, const float* __restrict__ b2) {
  __shared__ float sA[64*64];    // input tile (ci-major), later gelu j<64
  __shared__ float sB[64*64];    // gelu j>=64
  int blk = blockIdx.x;
  int b = blk / 1089;
  int flat0 = (blk - b*1089) * 64;
  int tid = threadIdx.x;
  int p = tid & 63;
  int cg = __builtin_amdgcn_readfirstlane(tid >> 6);  // 0..3 wave-uniform
  const float* xb = X + (size_t)b*CH*NPIX + flat0;
  #pragma unroll
  for (int i = 0; i < 16; ++i) {
    int idx = i*256 + tid;
    int ci = idx >> 6, pp = idx & 63;
    sA[idx] = xb[ci*NPIX + pp];
  }
  __syncthreads();
  // fused stage: (conv+mlp1) 64->128 + gelu; weights WfT[ci][cg*32..+32)
  float a1[32];
  #pragma unroll
  for (int j = 0; j < 32; ++j) a1[j] = bf[cg*32+j];
  #pragma unroll 2
  for (int ci = 0; ci < 64; ++ci) {
    float xv = sA[ci*64+p];
    const float* w = WfT + ci*128 + cg*32;
    #pragma unroll
    for (int j = 0; j < 32; ++j) a1[j] = fmaf(xv, w[j], a1[j]);
  }
  __syncthreads();   // all reads of sA done before gelu overwrites it
  if (cg < 2) {
    #pragma unroll
    for (int j = 0; j < 32; ++j) sA[(cg*32+j)*64+p] = gelu_erf(a1[j]);
  } else {
    #pragma unroll
    for (int j = 0; j < 32; ++j) sB[((cg-2)*32+j)*64+p] = gelu_erf(a1[j]);
  }
  __syncthreads();
  // stage 3: mlp2 128->64; weights W2T[j][cg*16..+16) contiguous
  float acc2[16];
  #pragma unroll
  for (int i = 0; i < 16; ++i) acc2[i] = b2[cg*16+i];
  #pragma unroll 4
  for (int j = 0; j < 64; ++j) {
    float xv = sA[j*64+p];
    const float* w = W2T + j*64 + cg*16;
    #pragma unroll
    for (int i = 0; i < 16; ++i) acc2[i] = fmaf(xv, w[i], acc2[i]);
  }
  #pragma unroll 4
  for (int j = 0; j < 64; ++j) {
    float xv = sB[j*64+p];
    const float* w = W2T + (j+64)*64 + cg*16;
    #pragma unroll
    for (int i = 0; i < 16; ++i) acc2[i] = fmaf(xv, w[i], acc2[i]);
  }
  float* hb = Hb + (size_t)b*CH*NPIX + flat0;
  #pragma unroll
  for (int i = 0; i < 16; ++i) hb[(cg*16+i)*NPIX + p] = acc2[i];
}

// ---------------- fwd-x DFT: F1[r][k] = sum_x X[r][x]*BX[x][k]
// k split 4-way across the block's 4 waves, w forced wave-uniform via
// readfirstlane so all BX loads scalarize to s_load_dwordx16.
__global__ __launch_bounds__(256, 4) void fwd_x_kernel(const float* __restrict__ X,
    float* __restrict__ F1, const float* __restrict__ BX) {
  int tid = threadIdx.x;
  int lane = tid & 63;
  int w = __builtin_amdgcn_readfirstlane(tid >> 6);   // k-chunk 0..3
  int k0 = w * 16;
  int r = blockIdx.x*64 + lane;
  const float* xr = X + (size_t)r*264;
  float acc[16];
  #pragma unroll
  for (int k = 0; k < 16; ++k) acc[k] = 0.f;
  float4 u = ((const float4*)xr)[0];
  float4 v = ((const float4*)xr)[1];
  #pragma unroll 1
  for (int xc = 0; xc < 33; ++xc) {
    int nc = (xc < 32) ? xc + 1 : 32;
    float4 nu = ((const float4*)xr)[nc*2];
    float4 nv = ((const float4*)xr)[nc*2+1];
    float xvv[8] = {u.x,u.y,u.z,u.w,v.x,v.y,v.z,v.w};
    #pragma unroll
    for (int i = 0; i < 8; ++i) {
      const float* B = BX + (xc*8+i)*64 + k0;
      #pragma unroll
      for (int k = 0; k < 16; ++k) acc[k] = fmaf(xvv[i], B[k], acc[k]);
    }
    u = nu; v = nv;
  }
  float* fr = F1 + (size_t)r*64 + k0;
  #pragma unroll
  for (int q = 0; q < 4; ++q)
    ((float4*)fr)[q] = make_float4(acc[4*q],acc[4*q+1],acc[4*q+2],acc[4*q+3]);
}

// ---------------- fwd-y DFT
__global__ __launch_bounds__(256, 4) void fwd_y_kernel(const float* __restrict__ F1,
    float* __restrict__ F2, const float2* __restrict__ csY) {
  __shared__ float sT[4][16][64];   // [y-chunk wave][k local][j]
  int tid = threadIdx.x, lane = tid & 63;
  int w = __builtin_amdgcn_readfirstlane(tid >> 6);
  int bc = blockIdx.x;
  int h = blockIdx.y;               // kx chunk 0..3
  float acc[16];
  #pragma unroll
  for (int k = 0; k < 16; ++k) acc[k] = 0.f;
  const float* f1b = F1 + (size_t)bc*264*64 + h*16;
  for (int y = w*66; y < (w+1)*66; ++y) {
    float2 cs = csY[y*64 + lane];
    float c = cs.x, s = cs.y, ns = -s;
    const float* fr = f1b + y*64;
    #pragma unroll
    for (int t = 0; t < 8; ++t) {
      float fre = fr[2*t], fim = fr[2*t+1];
      acc[2*t]   = fmaf(c, fre, fmaf(s,  fim, acc[2*t]));
      acc[2*t+1] = fmaf(c, fim, fmaf(ns, fre, acc[2*t+1]));
    }
  }
  #pragma unroll
  for (int k = 0; k < 16; ++k) sT[w][k][lane] = acc[k];
  __syncthreads();
  int j = tid >> 2, kg = tid & 3;
  float* out = F2 + (size_t)bc*4096 + j*64 + h*16 + kg*4;
  float o[4];
  #pragma unroll
  for (int t = 0; t < 4; ++t)
    o[t] = sT[0][kg*4+t][j] + sT[1][kg*4+t][j] + sT[2][kg*4+t][j] + sT[3][kg*4+t][j];
  *((float4*)out) = make_float4(o[0],o[1],o[2],o[3]);
}

// ---------------- per-mode channel mixing
__global__ __launch_bounds__(256) void mix_kernel(const float2* __restrict__ F2,
    float2* __restrict__ S,
    const float* __restrict__ w1r, const float* __restrict__ w1i,
    const float* __restrict__ w2r, const float* __restrict__ w2i) {
  int tid = threadIdx.x;
  int m = tid & 63;
  int cl = tid >> 6;
  int mode = blockIdx.x*64 + m;
  int co = blockIdx.y*4 + cl;
  int moff = mode & 1023;
  const float* wr = ((mode < 1024) ? w1r : w2r) + co*1024 + moff;
  const float* wi = ((mode < 1024) ? w1i : w2i) + co*1024 + moff;
  const float2* f2 = F2 + mode;
  float sr[4], si[4];
  #pragma unroll
  for (int b = 0; b < 4; ++b) { sr[b] = 0.f; si[b] = 0.f; }
  for (int ci = 0; ci < 64; ++ci) {
    float wrv = wr[(size_t)ci*65536];
    float wiv = wi[(size_t)ci*65536];
    #pragma unroll
    for (int b = 0; b < 4; ++b) {
      float2 f = f2[(size_t)(b*CH + ci)*2048];
      sr[b] = fmaf(f.x, wrv, fmaf(-f.y, wiv, sr[b]));
      si[b] = fmaf(f.x, wiv, fmaf( f.y, wrv, si[b]));
    }
  }
  #pragma unroll
  for (int b = 0; b < 4; ++b)
    S[((size_t)b*CH + co)*2048 + mode] = make_float2(sr[b], si[b]);
}

// ---------------- inv-y DFT
__global__ __launch_bounds__(256, 4) void inv_y_kernel(const float* __restrict__ S,
    float* __restrict__ Z, const float2* __restrict__ csYT) {
  int tid = threadIdx.x;
  int lane = tid & 63;
  int w = __builtin_amdgcn_readfirstlane(tid >> 6);   // kx chunk 0..3
  int bc = blockIdx.y;
  int y = blockIdx.x*64 + lane;
  int yy = (y < 264) ? y : 263;
  float acc[16];
  #pragma unroll
  for (int k = 0; k < 16; ++k) acc[k] = 0.f;
  const float* sb = S + (size_t)bc*4096 + w*16;
  for (int j = 0; j < 64; ++j) {
    float2 cs = csYT[j*264 + yy];
    float c = cs.x, s = cs.y, ns = -s;
    const float* sr = sb + j*64;
    #pragma unroll
    for (int t = 0; t < 8; ++t) {
      float sre = sr[2*t], sim = sr[2*t+1];
      acc[2*t]   = fmaf(c, sre, fmaf(ns, sim, acc[2*t]));
      acc[2*t+1] = fmaf(s, sre, fmaf(c,  sim, acc[2*t+1]));
    }
  }
  if (y < 264) {
    float* zr = Z + ((size_t)bc*264 + y)*64 + w*16;
    #pragma unroll
    for (int q = 0; q < 4; ++q)
      ((float4*)zr)[q] = make_float4(acc[4*q],acc[4*q+1],acc[4*q+2],acc[4*q+3]);
  }
}

// ---------------- inv-x irfft + Hb add + store (crop on last layer)
__global__ __launch_bounds__(128) void inv_x_kernel(const float* __restrict__ Z,
    const float* __restrict__ Hb, float* __restrict__ Xout, float* __restrict__ Dout,
    const float* __restrict__ BI, int last) {
  int r = blockIdx.x*128 + threadIdx.x;
  int xh = blockIdx.y;
  float a[64];
  const float4* zp = (const float4*)(Z + (size_t)r*64);
  #pragma unroll
  for (int q = 0; q < 16; ++q) {
    float4 t = zp[q];
    a[4*q] = t.x; a[4*q+1] = t.y; a[4*q+2] = t.z; a[4*q+3] = t.w;
  }
  int y = r % 264;
  int bc = r / 264;
  const float* hbr = Hb + (size_t)r*264;
  float* xo = Xout + (size_t)r*264;
  float* dor = Dout + ((size_t)bc*256 + y)*256;
  #pragma unroll 1
  for (int cch = 0; cch < 4; ++cch) {
    int x0 = xh*128 + cch*32;
    float acc[32];
    #pragma unroll
    for (int s = 0; s < 32; ++s) acc[s] = 0.f;
    #pragma unroll
    for (int k = 0; k < 64; ++k) {
      const float* B = BI + (size_t)k*264 + x0;
      #pragma unroll
      for (int s = 0; s < 32; ++s) acc[s] = fmaf(a[k], B[s], acc[s]);
    }
    if (!last) {
      #pragma unroll
      for (int q = 0; q < 8; ++q) {
        float4 h = ((const float4*)(hbr + x0))[q];
        ((float4*)(xo + x0))[q] =
          make_float4(h.x+acc[4*q], h.y+acc[4*q+1], h.z+acc[4*q+2], h.w+acc[4*q+3]);
      }
    } else if (y < 256) {
      #pragma unroll
      for (int q = 0; q < 8; ++q) {
        float4 h = ((const float4*)(hbr + x0))[q];
        ((float4*)(dor + x0))[q] =
          make_float4(h.x+acc[4*q], h.y+acc[4*q+1], h.z+acc[4*q+2], h.w+acc[4*q+3]);
      }
    }
  }
  if (xh == 1 && !last) {
    float acc[8];
    #pragma unroll
    for (int s = 0; s < 8; ++s) acc[s] = 0.f;
    #pragma unroll
    for (int k = 0; k < 64; ++k) {
      const float* B = BI + (size_t)k*264 + 256;
      #pragma unroll
      for (int s = 0; s < 8; ++s) acc[s] = fmaf(a[k], B[s], acc[s]);
    }
    #pragma unroll
    for (int q = 0; q < 2; ++q) {
      float4 h = ((const float4*)(hbr + 256))[q];
      ((float4*)(xo + 256))[q] =
        make_float4(h.x+acc[4*q], h.y+acc[4*q+1], h.z+acc[4*q+2], h.w+acc[4*q+3]);
    }
  }
}

extern "C" void kernel_launch(void* const* d_in, const int* in_sizes, int n_in,
                              void* d_out, int out_size, void* d_ws, size_t ws_size,
                              hipStream_t stream) {
  (void)in_sizes; (void)n_in; (void)out_size; (void)ws_size;
  const float* x_in   = (const float*)d_in[0];
  const float* lw1    = (const float*)d_in[1];
  const float* lb1    = (const float*)d_in[2];
  const float* lw2    = (const float*)d_in[3];
  const float* lb2    = (const float*)d_in[4];
  const float* conv_w = (const float*)d_in[5];
  const float* conv_b = (const float*)d_in[6];
  const float* mlp_w1 = (const float*)d_in[7];
  const float* mlp_b1 = (const float*)d_in[8];
  const float* mlp_w2 = (const float*)d_in[9];
  const float* mlp_b2 = (const float*)d_in[10];
  const float* sw1r   = (const float*)d_in[11];
  const float* sw1i   = (const float*)d_in[12];
  const float* sw2r   = (const float*)d_in[13];
  const float* sw2i   = (const float*)d_in[14];
  float* dout = (float*)d_out;

  float* ws = (float*)d_ws;
  size_t off = 0;
  float*  xbuf = ws + off;          off += (size_t)BCN*NPIX;
  float*  hbuf = ws + off;          off += (size_t)BCN*NPIX;
  float*  F1   = ws + off;          off += (size_t)NROWS*64;   // also Z
  float*  F2   = ws + off;          off += (size_t)BCN*4096;
  float*  S    = ws + off;          off += (size_t)BCN*4096;
  float*  BX   = ws + off;          off += 264*64;
  float*  BI   = ws + off;          off += 264*64;
  float2* csY  = (float2*)(ws+off); off += 264*64*2;
  float2* csYT = (float2*)(ws+off); off += 264*64*2;
  float*  WfT  = ws + off;          off += 3*8192;
  float*  bff  = ws + off;          off += 3*128;
  float*  W2T  = ws + off;          off += 3*8192;

  init_tables<<<66, 256, 0, stream>>>(BX, BI, csY, csYT);
  fuse_weights<<<96, 256, 0, stream>>>(conv_w, conv_b, mlp_w1, mlp_b1, WfT, bff);
  transpose_w2<<<96, 256, 0, stream>>>(mlp_w2, W2T);
  lift_kernel<<<dim3(273, 4), 256, 0, stream>>>(x_in, lw1, lb1, lw2, lb2, xbuf);

  for (int k = 0; k < 3; ++k) {
    convmlp_kernel<<<4356, 256, 0, stream>>>(xbuf, hbuf,
        WfT + k*8192, bff + k*128,
        W2T + k*8192, mlp_b2 + k*64);
    fwd_x_kernel<<<1056, 256, 0, stream>>>(xbuf, F1, BX);
    fwd_y_kernel<<<dim3(256, 4), 256, 0, stream>>>(F1, F2, csY);
    mix_kernel<<<dim3(32, 16), 256, 0, stream>>>((const float2*)F2, (float2*)S,
        sw1r + (size_t)k*4194304, sw1i + (size_t)k*4194304,
        sw2r + (size_t)k*4194304, sw2i + (size_t)k*4194304);
    inv_y_kernel<<<dim3(5, 256), 256, 0, stream>>>(S, F1, csYT);
    inv_x_kernel<<<dim3(528, 2), 128, 0, stream>>>(F1, hbuf, xbuf, dout, BI, (k==2)?1:0);
  }
}